// Round 16
// baseline (181.301 us; speedup 1.0000x reference)
//
#include <hip/hip_runtime.h>
#include <hip/hip_bf16.h>

// ---------------------------------------------------------------------------
// OutliersQLinearColumn: out = x @ w^T + bias,  w = s_o*sign(weight-mean_o)
// with fp32 outlier columns scattered in (last-wins).
// Round 16: BK=128 fixed-overhead amortization. 256x256 tile, 8 waves,
// mfma_i32_16x16x64_i8, 2 LDS bufs x 64 KB (NT=34, half the barriers/waits).
// 128-B LDS rows -> 8-slot XOR swizzle: phys16Bslot = logical ^ (row&7),
// applied on stage-source and read side (gload_lds dest stays linear,
// wave-contiguous base+lane*16). Per tile: {STAGE(t+1); MFMA KH0(preloaded);
// READS KH1; MFMA KH1; vmcnt(0); barrier; shadow-READS KH0(t+1)}.
// Prep: R12's fused 2-kernel version (proven).
// ---------------------------------------------------------------------------

typedef __attribute__((ext_vector_type(4))) int i32x4;

// ---------------------------------------------------------------------------
// Weight row -> mean, scale, qw = 8*sign (main) + correction cols.
// ---------------------------------------------------------------------------
__global__ void quant_sign_kernel(const float* __restrict__ w,
                                  const float* __restrict__ ow,
                                  const int* __restrict__ idx,
                                  signed char* __restrict__ qw,
                                  float* __restrict__ sArr,
                                  int IC, int K2, int n_out) {
    __shared__ float red[8];
    __shared__ signed char sgn[4096];
    __shared__ int cmL[4096];
    const int o = blockIdx.x;
    const int t = threadIdx.x;
    const int lane = t & 63, wid = t >> 6;

#pragma unroll
    for (int i = 0; i < 16; ++i) cmL[t + i * 256] = -1;

    const float4* row4 = (const float4*)(w + (size_t)o * IC);
    float4 v[4];
    float s = 0.f;
#pragma unroll
    for (int j = 0; j < 4; ++j) {
        v[j] = row4[t + j * 256];
        s += v[j].x + v[j].y + v[j].z + v[j].w;
    }
#pragma unroll
    for (int off = 32; off; off >>= 1) s += __shfl_down(s, off);
    if (lane == 0) red[wid] = s;
    __syncthreads();
    const float mean = (red[0] + red[1] + red[2] + red[3]) / (float)IC;

    if (t < n_out) atomicMax(&cmL[idx[t]], t);

    float a = 0.f;
#pragma unroll
    for (int j = 0; j < 4; ++j)
        a += fabsf(v[j].x - mean) + fabsf(v[j].y - mean) +
             fabsf(v[j].z - mean) + fabsf(v[j].w - mean);
#pragma unroll
    for (int off = 32; off; off >>= 1) a += __shfl_down(a, off);
    if (lane == 0) red[4 + wid] = a;
    __syncthreads();
    const float scale = (red[4] + red[5] + red[6] + red[7]) / (float)IC;
    if (t == 0) sArr[o] = scale;

    const size_t base = (size_t)o * K2;
#pragma unroll
    for (int j = 0; j < 4; ++j) {
        const int c0 = (t + j * 256) * 4;
        float ee[4] = {v[j].x, v[j].y, v[j].z, v[j].w};
        int pack = 0;
#pragma unroll
        for (int ei = 0; ei < 4; ++ei) {
            float c = ee[ei] - mean;
            int q = c > 0.f ? 8 : (c < 0.f ? -8 : 0);
            pack |= (q & 0xff) << (ei * 8);
        }
        *(int*)(qw + base + c0) = pack;
        *(int*)(sgn + c0) = pack;
    }
    __syncthreads();

    signed char q = 0;
    if (t < n_out) {
        const int c = idx[t];
        if (cmL[c] == t) {
            const float sg = (float)sgn[c] * 0.125f;   // +-1 or 0
            const float wc = ow[(size_t)o * n_out + t] - scale * sg;
            float qf = rintf(8.f * wc / scale);
            qf = fminf(127.f, fmaxf(-127.f, qf));
            q = (signed char)(int)qf;
        }
    }
    qw[base + IC + t] = q;
}

// ---------------------------------------------------------------------------
// x row -> D_m, qx = rint(x/D_m) (main) + gathered correction cols (fused).
// ---------------------------------------------------------------------------
__global__ void quant_x_kernel(const float4* __restrict__ x4,
                               const int* __restrict__ idx,
                               signed char* __restrict__ qx,
                               float* __restrict__ rdel,
                               int IC, int K2, int n_out) {
    __shared__ float red[4];
    __shared__ float bmax;
    __shared__ signed char rowq[4096];
    const int m = blockIdx.x;
    const int t = threadIdx.x;
    const int lane = t & 63, wid = t >> 6;

    const float4* row4 = x4 + (size_t)m * (IC / 4);
    float4 v[4];
    float mx = 0.f;
#pragma unroll
    for (int j = 0; j < 4; ++j) {
        v[j] = row4[t + j * 256];
        mx = fmaxf(mx, fmaxf(fmaxf(fabsf(v[j].x), fabsf(v[j].y)),
                             fmaxf(fabsf(v[j].z), fabsf(v[j].w))));
    }
#pragma unroll
    for (int off = 32; off; off >>= 1) mx = fmaxf(mx, __shfl_down(mx, off));
    if (lane == 0) red[wid] = mx;
    __syncthreads();
    if (t == 0) {
        float m0 = fmaxf(fmaxf(red[0], red[1]), fmaxf(red[2], red[3]));
        bmax = m0;
        rdel[m] = m0 / 127.f;
    }
    __syncthreads();
    const float inv = 127.f / bmax;

    const size_t base = (size_t)m * K2;
#pragma unroll
    for (int j = 0; j < 4; ++j) {
        const int c0 = (t + j * 256) * 4;
        float ee[4] = {v[j].x, v[j].y, v[j].z, v[j].w};
        int pack = 0;
#pragma unroll
        for (int ei = 0; ei < 4; ++ei) {
            int q = (int)rintf(ee[ei] * inv);
            pack |= (q & 0xff) << (ei * 8);
        }
        *(int*)(qx + base + c0) = pack;
        *(int*)(rowq + c0) = pack;
    }
    __syncthreads();

    signed char g = 0;
    if (t < n_out) g = rowq[idx[t]];
    qx[base + IC + t] = g;
}

// ---------------------------------------------------------------------------
// i8 GEMM, BK=128: acc[m,o] = sum_k qx[m,k]*qw[o,k]; out = acc*(s_o*D_m/8)+b.
// 512 thr = 8 waves (2M x 4N), per-wave 128x64 = 8(mi) x 4(ni) frags 16x16.
// LDS: 2 bufs x [mat2][256 rows][128 B] (strides 65536/32768/128 B).
// 8-slot swizzle: physical 16B-slot p = logical l ^ (row&7).
//   stage: thread u -> row u>>3 (+64p), dest slot u&7 (linear, wave-contig);
//          global source slot = (u&7) ^ ((u>>3)&7).
//   read: logical l = (lane>>4) + KH*4, row&7 = lane&7 ->
//         slK0 = ((lane>>4)^(lane&7))*16, slK1 = slK0 ^ 64.
//   16-lane group: 8 phys slots x 2 lanes = 32 banks 2-way (free).
// Tile body (1 barrier / 128 K):
//   STAGE(t+1, 8 loads) ; MFMA KH0 (preloaded regs) ; READS KH1 ;
//   MFMA KH1 ; vmcnt(0) [drains t+1's stages, issued ~1 tile earlier] ;
//   barrier ; shadow-READS KH0 of t+1.
// WAR: KH1 reads of buf t precede MFMA KH1 which precedes the barrier;
// buf t is overwritten by STAGE(t+2) only after that barrier.
// ---------------------------------------------------------------------------
#define GLDS(src, dst) __builtin_amdgcn_global_load_lds( \
    (const __attribute__((address_space(1))) void*)(src), \
    (__attribute__((address_space(3))) void*)(dst), 16, 0, 0)

// Stage matrix MAT (0=A,1=B) of the BK128 tile at byte k-offset knB -> bufS.
#define STAGE128(MAT, bufS, knB) do {                                         \
    const signed char* gsrc_ = (MAT) ? Bblk : Ablk;                           \
    _Pragma("unroll")                                                         \
    for (int p_ = 0; p_ < 4; ++p_) {                                          \
      GLDS(gsrc_ + (size_t)(p_ * 64 + stg_row2) * K2 + (knB) + stg_col2,      \
           &ldsb[(bufS) * 65536 + (MAT) * 32768 +                             \
                 (p_ * 64 + stg_row2) * 128 + stg_dst2]);                     \
    } } while (0)

// A-fragment reads (4 x ds_read_b128) for frag-half FH, slot const SL, buf B_
#define RDA(AF, FH, SL, B_) do {                                              \
    const signed char* pa_ = &ldsb[(B_) * 65536];                             \
    _Pragma("unroll")                                                         \
    for (int j_ = 0; j_ < 4; ++j_)                                            \
      AF[j_] = *(const i32x4*)&pa_[(wr * 128 + ((FH) * 4 + j_) * 16 + l15) * 128 + (SL)]; \
  } while (0)

// B-fragment reads (4 x ds_read_b128), slot const SL, buf B_
#define RDB(BF, SL, B_) do {                                                  \
    const signed char* pb_ = &ldsb[(B_) * 65536 + 32768];                     \
    _Pragma("unroll")                                                         \
    for (int j_ = 0; j_ < 4; ++j_)                                            \
      BF[j_] = *(const i32x4*)&pb_[(wc * 64 + j_ * 16 + l15) * 128 + (SL)];   \
  } while (0)

#define MM16(AF, FH) do {                                                     \
    _Pragma("unroll")                                                         \
    for (int mi_ = 0; mi_ < 4; ++mi_)                                         \
      _Pragma("unroll")                                                       \
      for (int ni_ = 0; ni_ < 4; ++ni_)                                       \
        acc[(FH) * 4 + mi_][ni_] = __builtin_amdgcn_mfma_i32_16x16x64_i8(     \
            AF[mi_], bfr[ni_], acc[(FH) * 4 + mi_][ni_], 0, 0, 0);            \
  } while (0)

// One BK128 tile: read bufR (KH0 preloaded), stage t+1 -> bufS, shadow-read
// t+1's KH0 from bufS at the end.
#define KT128(bufR, bufS, knB) do {                                           \
    STAGE128(0, bufS, knB);                                                   \
    STAGE128(1, bufS, knB);                                                   \
    __builtin_amdgcn_s_setprio(1);                                            \
    MM16(afr0, 0);                                                            \
    MM16(afr1, 1);                                                            \
    __builtin_amdgcn_s_setprio(0);                                            \
    RDB(bfr, slK1, bufR);                                                     \
    RDA(afr0, 0, slK1, bufR);                                                 \
    RDA(afr1, 1, slK1, bufR);                                                 \
    __builtin_amdgcn_s_setprio(1);                                            \
    MM16(afr0, 0);                                                            \
    MM16(afr1, 1);                                                            \
    __builtin_amdgcn_s_setprio(0);                                            \
    asm volatile("s_waitcnt vmcnt(0)" ::: "memory");                          \
    __builtin_amdgcn_s_barrier();                                             \
    RDB(bfr, slK0, bufS);                                                     \
    RDA(afr0, 0, slK0, bufS);                                                 \
    RDA(afr1, 1, slK0, bufS);                                                 \
  } while (0)

__global__ __launch_bounds__(512, 2) void gemm_i8_kernel(
    const signed char* __restrict__ Aq,   // [M, K2] i8
    const signed char* __restrict__ Bq,   // [OC, K2] i8
    const float* __restrict__ bias,       // [OC]
    const float* __restrict__ sArr,       // [OC]
    const float* __restrict__ rdel,       // [M]
    float* __restrict__ C,                // [M, OC] f32
    int M, int N, int K2, int NBN) {
    extern __shared__ signed char ldsb[];  // 131072 B = 2 bufs x 64 KiB

    const int t = threadIdx.x;
    const int wid = t >> 6, lane = t & 63;
    const int l15 = lane & 15;
    const int slK0 = (((lane >> 4) ^ (lane & 7)) & 7) * 16;   // KH0 slot (bytes)
    const int slK1 = slK0 ^ 64;                               // KH1 slot
    const int wr = wid >> 2;                  // 0..1  (M half)
    const int wc = wid & 3;                   // 0..3  (N quarter)
    const int stg_row2 = t >> 3;              // 0..63
    const int stg_col2 = (((t & 7) ^ ((t >> 3) & 7)) & 7) * 16;  // src bytes
    const int stg_dst2 = (t & 7) * 16;                           // dest bytes

    // bijective XCD swizzle
    const int nwg = gridDim.x;
    const int bid = blockIdx.x;
    const int q = nwg >> 3, r = nwg & 7;
    const int xcd = bid & 7, off = bid >> 3;
    const int swz = (xcd < r ? xcd * (q + 1) : r * (q + 1) + (xcd - r) * q) + off;
    const int bm = swz / NBN, bn = swz % NBN;

    const signed char* Ablk = Aq + (size_t)(bm * 256) * K2;
    const signed char* Bblk = Bq + (size_t)(bn * 256) * K2;

    i32x4 acc[8][4] = {};
    i32x4 afr0[4], afr1[4], bfr[4];

    // ---- prologue: stage tile0 -> buf0; drain; pre-read tile0 KH0 ----
    STAGE128(0, 0, 0);
    STAGE128(1, 0, 0);
    asm volatile("s_waitcnt vmcnt(0)" ::: "memory");
    __builtin_amdgcn_s_barrier();
    RDB(bfr, slK0, 0);
    RDA(afr0, 0, slK0, 0);
    RDA(afr1, 1, slK0, 0);

    // NT = K2/128 = 34 tiles = 17 iterations x 2. Tile tt: read buf tt&1,
    // stage tile tt+1 -> buf (tt+1)&1. Last body stages kn=0 (dead) and
    // shadow-reads dead data (never consumed) -- all in-bounds.
    for (int it = 0; it < 17; ++it) {
        const int k1 = (2 * it + 1) * 128;                       // live
        const int k2 = (2 * it + 2 < 34) ? (2 * it + 2) * 128 : 0;
        KT128(0, 1, k1);
        KT128(1, 0, k2);
    }

    // ---- epilogue: out = acc*(s_o*D_m/8) + bias ----
    // C/D layout: col = lane&15, row = (lane>>4)*4 + reg
    float sv[4], bv[4];
#pragma unroll
    for (int ni = 0; ni < 4; ++ni) {
        const int col = bn * 256 + wc * 64 + ni * 16 + l15;
        sv[ni] = sArr[col] * 0.125f;
        bv[ni] = bias[col];
    }

    const int crow0 = bm * 256 + wr * 128;
    const int ccol = bn * 256 + wc * 64 + l15;
#pragma unroll
    for (int mi = 0; mi < 8; ++mi) {
#pragma unroll
        for (int rr = 0; rr < 4; ++rr) {
            const int row = crow0 + mi * 16 + (lane >> 4) * 4 + rr;
            const float rd = rdel[row];
            float* Crow = C + (size_t)row * N;
#pragma unroll
            for (int ni = 0; ni < 4; ++ni)
                Crow[ccol + ni * 16] =
                    (float)acc[mi][ni][rr] * (sv[ni] * rd) + bv[ni];
        }
    }
}

// ---------------------------------------------------------------------------
extern "C" void kernel_launch(void* const* d_in, const int* in_sizes, int n_in,
                              void* d_out, int out_size, void* d_ws, size_t ws_size,
                              hipStream_t stream) {
    const float* x      = (const float*)d_in[0];
    const float* weight = (const float*)d_in[1];
    const float* bias   = (const float*)d_in[2];
    const float* ow     = (const float*)d_in[3];
    const int*   idx    = (const int*)d_in[4];

    const int OC    = in_sizes[2];
    const int n_out = in_sizes[4];
    const int IC    = in_sizes[1] / OC;      // 4096
    const int M     = in_sizes[0] / IC;      // 8192
    const int K2    = IC + 256;              // 4352
    float* out = (float*)d_out;

    char* ws = (char*)d_ws;
    signed char* qx = (signed char*)ws;                                 // M*K2
    signed char* qw = (signed char*)(ws + (size_t)M * K2);              // OC*K2
    float* sArr = (float*)(ws + (size_t)M * K2 + (size_t)OC * K2);      // OC
    float* rdel = sArr + OC;                                            // M

    quant_sign_kernel<<<OC, 256, 0, stream>>>(weight, ow, idx, qw, sArr,
                                              IC, K2, n_out);
    quant_x_kernel<<<M, 256, 0, stream>>>((const float4*)x, idx, qx, rdel,
                                          IC, K2, n_out);

    hipFuncSetAttribute((const void*)gemm_i8_kernel,
                        hipFuncAttributeMaxDynamicSharedMemorySize, 131072);
    const int NBM = M / 256, NBN = OC / 256;
    gemm_i8_kernel<<<dim3(NBM * NBN), dim3(512), 131072, stream>>>(
        qx, qw, bias, sArr, rdel, out, M, OC, K2, NBN);
}

// Round 17
// 178.968 us; speedup vs baseline: 1.0130x; 1.0130x over previous
//
#include <hip/hip_runtime.h>
#include <hip/hip_bf16.h>

// ---------------------------------------------------------------------------
// OutliersQLinearColumn: out = x @ w^T + bias,  w = s_o*sign(weight-mean_o)
// with fp32 outlier columns scattered in (last-wins).
// Round 17 = Round 15 verbatim (measured best: 178.5 us total, GEMM 126.6).
// Shadow-read schedule. Tile body:
//   { STAGE(t+3) ; vmcnt(8) ; barrier ; 32 MFMA(t) ; 12 READS(t+1) }
// 256x256, 8 waves, mfma_i32_16x16x64_i8, 4 bufs x 32 KB, slot-XOR swizzle
// (measured 0 conflicts), counted vmcnt(8) 3-tile pipeline, 1 barrier/tile.
// Prep: fused 2-kernel quantization (measured ~52 us, at memory floor).
// ---------------------------------------------------------------------------

typedef __attribute__((ext_vector_type(4))) int i32x4;

// ---------------------------------------------------------------------------
// Weight row -> mean, scale, qw = 8*sign (main) + correction cols.
// colmap (last-wins winner per column) rebuilt per block in LDS.
// ---------------------------------------------------------------------------
__global__ void quant_sign_kernel(const float* __restrict__ w,
                                  const float* __restrict__ ow,
                                  const int* __restrict__ idx,
                                  signed char* __restrict__ qw,
                                  float* __restrict__ sArr,
                                  int IC, int K2, int n_out) {
    __shared__ float red[8];
    __shared__ signed char sgn[4096];
    __shared__ int cmL[4096];
    const int o = blockIdx.x;
    const int t = threadIdx.x;
    const int lane = t & 63, wid = t >> 6;

#pragma unroll
    for (int i = 0; i < 16; ++i) cmL[t + i * 256] = -1;

    const float4* row4 = (const float4*)(w + (size_t)o * IC);
    float4 v[4];
    float s = 0.f;
#pragma unroll
    for (int j = 0; j < 4; ++j) {
        v[j] = row4[t + j * 256];
        s += v[j].x + v[j].y + v[j].z + v[j].w;
    }
#pragma unroll
    for (int off = 32; off; off >>= 1) s += __shfl_down(s, off);
    if (lane == 0) red[wid] = s;
    __syncthreads();
    const float mean = (red[0] + red[1] + red[2] + red[3]) / (float)IC;

    if (t < n_out) atomicMax(&cmL[idx[t]], t);

    float a = 0.f;
#pragma unroll
    for (int j = 0; j < 4; ++j)
        a += fabsf(v[j].x - mean) + fabsf(v[j].y - mean) +
             fabsf(v[j].z - mean) + fabsf(v[j].w - mean);
#pragma unroll
    for (int off = 32; off; off >>= 1) a += __shfl_down(a, off);
    if (lane == 0) red[4 + wid] = a;
    __syncthreads();
    const float scale = (red[4] + red[5] + red[6] + red[7]) / (float)IC;
    if (t == 0) sArr[o] = scale;

    const size_t base = (size_t)o * K2;
#pragma unroll
    for (int j = 0; j < 4; ++j) {
        const int c0 = (t + j * 256) * 4;
        float ee[4] = {v[j].x, v[j].y, v[j].z, v[j].w};
        int pack = 0;
#pragma unroll
        for (int ei = 0; ei < 4; ++ei) {
            float c = ee[ei] - mean;
            int q = c > 0.f ? 8 : (c < 0.f ? -8 : 0);
            pack |= (q & 0xff) << (ei * 8);
        }
        *(int*)(qw + base + c0) = pack;
        *(int*)(sgn + c0) = pack;
    }
    __syncthreads();

    signed char q = 0;
    if (t < n_out) {
        const int c = idx[t];
        if (cmL[c] == t) {
            const float sg = (float)sgn[c] * 0.125f;   // +-1 or 0
            const float wc = ow[(size_t)o * n_out + t] - scale * sg;
            float qf = rintf(8.f * wc / scale);
            qf = fminf(127.f, fmaxf(-127.f, qf));
            q = (signed char)(int)qf;
        }
    }
    qw[base + IC + t] = q;
}

// ---------------------------------------------------------------------------
// x row -> D_m, qx = rint(x/D_m) (main) + gathered correction cols (fused).
// ---------------------------------------------------------------------------
__global__ void quant_x_kernel(const float4* __restrict__ x4,
                               const int* __restrict__ idx,
                               signed char* __restrict__ qx,
                               float* __restrict__ rdel,
                               int IC, int K2, int n_out) {
    __shared__ float red[4];
    __shared__ float bmax;
    __shared__ signed char rowq[4096];
    const int m = blockIdx.x;
    const int t = threadIdx.x;
    const int lane = t & 63, wid = t >> 6;

    const float4* row4 = x4 + (size_t)m * (IC / 4);
    float4 v[4];
    float mx = 0.f;
#pragma unroll
    for (int j = 0; j < 4; ++j) {
        v[j] = row4[t + j * 256];
        mx = fmaxf(mx, fmaxf(fmaxf(fabsf(v[j].x), fabsf(v[j].y)),
                             fmaxf(fabsf(v[j].z), fabsf(v[j].w))));
    }
#pragma unroll
    for (int off = 32; off; off >>= 1) mx = fmaxf(mx, __shfl_down(mx, off));
    if (lane == 0) red[wid] = mx;
    __syncthreads();
    if (t == 0) {
        float m0 = fmaxf(fmaxf(red[0], red[1]), fmaxf(red[2], red[3]));
        bmax = m0;
        rdel[m] = m0 / 127.f;
    }
    __syncthreads();
    const float inv = 127.f / bmax;

    const size_t base = (size_t)m * K2;
#pragma unroll
    for (int j = 0; j < 4; ++j) {
        const int c0 = (t + j * 256) * 4;
        float ee[4] = {v[j].x, v[j].y, v[j].z, v[j].w};
        int pack = 0;
#pragma unroll
        for (int ei = 0; ei < 4; ++ei) {
            int q = (int)rintf(ee[ei] * inv);
            pack |= (q & 0xff) << (ei * 8);
        }
        *(int*)(qx + base + c0) = pack;
        *(int*)(rowq + c0) = pack;
    }
    __syncthreads();

    signed char g = 0;
    if (t < n_out) g = rowq[idx[t]];
    qx[base + IC + t] = g;
}

// ---------------------------------------------------------------------------
// i8 GEMM: acc[m,o] = sum_k qx[m,k]*qw[o,k]; out = acc*(s_o*D_m/8) + bias.
// 512 thr = 8 waves (2M x 4N), per-wave 128x64 = 8(mi) x 4(ni) frags 16x16,
// mfma_i32_16x16x64_i8. LDS: 4 bufs x 32 KB, slot-XOR swizzle (0 conflicts).
// Shadow-read tile body (1 barrier/tile):
//   STAGE(t+3) ; vmcnt(8) [drains t+1's stages: 12 outstanding -> 8] ;
//   barrier [cross-thread visibility of buf t+1] ;
//   setprio(1) ; 32 MFMA(t) [regs read in tile t-1's shadow] ; setprio(0) ;
//   RDB+RDA0+RDA1 of tile t+1 [12 ds_reads complete under MFMA drain]
// WAR: reads(t+1) < MFMA(t+1) < barrier(t+2) < stage(t+5) overwriting
// buf t+1. Reg WAR: MFMA consumes operands at issue; reads reuse same regs.
// ---------------------------------------------------------------------------
#define GLDS(src, dst) __builtin_amdgcn_global_load_lds( \
    (const __attribute__((address_space(1))) void*)(src), \
    (__attribute__((address_space(3))) void*)(dst), 16, 0, 0)

// Stage matrix MAT (0=A,1=B) of the BK64 tile at byte k-offset knB into bufS.
#define STAGE64(MAT, bufS, knB) do {                                          \
    const signed char* gsrc_ = (MAT) ? Bblk : Ablk;                           \
    _Pragma("unroll")                                                         \
    for (int rr_ = 0; rr_ < 2; ++rr_) {                                       \
      GLDS(gsrc_ + (size_t)(rr_ * 128 + stg_row) * K2 + (knB) + stg_col,      \
           &ldsb[(bufS) * 32768 + (MAT) * 16384 + (rr_ * 128 + wid * 16) * 64]); \
    } } while (0)

// A-fragment reads (4 x ds_read_b128) for fragment-half FH from buf B_
#define RDA(AF, FH, B_) do {                                                  \
    const signed char* pa_ = &ldsb[(B_) * 32768];                             \
    _Pragma("unroll")                                                         \
    for (int j_ = 0; j_ < 4; ++j_)                                            \
      AF[j_] = *(const i32x4*)&pa_[(wr * 128 + ((FH) * 4 + j_) * 16 + l15) * 64 + slB]; \
  } while (0)

// B-fragment reads (4 x ds_read_b128) from buf B_
#define RDB(BF, B_) do {                                                      \
    const signed char* pb_ = &ldsb[(B_) * 32768 + 16384];                     \
    _Pragma("unroll")                                                         \
    for (int j_ = 0; j_ < 4; ++j_)                                            \
      BF[j_] = *(const i32x4*)&pb_[(wc * 64 + j_ * 16 + l15) * 64 + slB];     \
  } while (0)

#define MM16(AF, FH) do {                                                     \
    _Pragma("unroll")                                                         \
    for (int mi_ = 0; mi_ < 4; ++mi_)                                         \
      _Pragma("unroll")                                                       \
      for (int ni_ = 0; ni_ < 4; ++ni_)                                       \
        acc[(FH) * 4 + mi_][ni_] = __builtin_amdgcn_mfma_i32_16x16x64_i8(     \
            AF[mi_], bfr[ni_], acc[(FH) * 4 + mi_][ni_], 0, 0, 0);            \
  } while (0)

// One K-tile: stage t+3 -> bufS, fence+barrier, MFMA tile t (preloaded regs),
// then read tile t+1's fragments from bufN in the MFMA shadow.
#define KT64(bufN, bufS, knB) do {                                            \
    STAGE64(0, bufS, knB);                                                    \
    STAGE64(1, bufS, knB);                                                    \
    asm volatile("s_waitcnt vmcnt(8)" ::: "memory");                          \
    __builtin_amdgcn_s_barrier();                                             \
    __builtin_amdgcn_s_setprio(1);                                            \
    MM16(afr0, 0);                                                            \
    MM16(afr1, 1);                                                            \
    __builtin_amdgcn_s_setprio(0);                                            \
    RDB(bfr, bufN);                                                           \
    RDA(afr0, 0, bufN);                                                       \
    RDA(afr1, 1, bufN);                                                       \
  } while (0)

__global__ __launch_bounds__(512, 2) void gemm_i8_kernel(
    const signed char* __restrict__ Aq,   // [M, K2] i8
    const signed char* __restrict__ Bq,   // [OC, K2] i8
    const float* __restrict__ bias,       // [OC]
    const float* __restrict__ sArr,       // [OC]
    const float* __restrict__ rdel,       // [M]
    float* __restrict__ C,                // [M, OC] f32
    int M, int N, int K2, int NBN) {
    extern __shared__ signed char ldsb[];  // 131072 B = 4 x 32 KiB buffers

    const int t = threadIdx.x;
    const int wid = t >> 6, lane = t & 63;
    const int l15 = lane & 15;
    const int slB = (((lane >> 4) ^ ((lane >> 1) & 3)) & 3) * 16;  // read slot
    const int wr = wid >> 2;                  // 0..1  (M half)
    const int wc = wid & 3;                   // 0..3  (N quarter)
    const int stg_row = wid * 16 + (lane >> 2);
    const int stg_col = (((lane & 3) ^ ((lane >> 3) & 3)) & 3) * 16;  // bytes

    // bijective XCD swizzle
    const int nwg = gridDim.x;
    const int bid = blockIdx.x;
    const int q = nwg >> 3, r = nwg & 7;
    const int xcd = bid & 7, off = bid >> 3;
    const int swz = (xcd < r ? xcd * (q + 1) : r * (q + 1) + (xcd - r) * q) + off;
    const int bm = swz / NBN, bn = swz % NBN;

    const signed char* Ablk = Aq + (size_t)(bm * 256) * K2;
    const signed char* Bblk = Bq + (size_t)(bn * 256) * K2;

    i32x4 acc[8][4] = {};
    i32x4 afr0[4], afr1[4], bfr[4];

    // ---- prologue: stage tiles 0,1,2 -> bufs 0,1,2; drain tile0;
    //      pre-read tile0's fragments ----
    STAGE64(0, 0, 0);    STAGE64(1, 0, 0);
    STAGE64(0, 1, 64);   STAGE64(1, 1, 64);
    STAGE64(0, 2, 128);  STAGE64(1, 2, 128);
    asm volatile("s_waitcnt vmcnt(8)" ::: "memory");
    __builtin_amdgcn_s_barrier();
    RDB(bfr, 0);
    RDA(afr0, 0, 0);
    RDA(afr1, 1, 0);

    // NT = K2/64 = 68 tiles = 17 iterations x 4. Tile t: stage t+3 into
    // (t+3)%4, MFMA t (preloaded), shadow-read t+1 from (t+1)%4.
    // Tail: dead stages (kn=0) and one dead read (t=67 reads buf0 garbage,
    // never consumed) -- all in-bounds.
    for (int it = 0; it < 17; ++it) {
        const int tt = it * 4;
        const int k3 = (tt + 3) * 64;                        // <= 67*64, live
        const int k4 = (tt + 4 < 68) ? (tt + 4) * 64 : 0;    // dead at end
        const int k5 = (tt + 5 < 68) ? (tt + 5) * 64 : 0;
        const int k6 = (tt + 6 < 68) ? (tt + 6) * 64 : 0;
        KT64(1, 3, k3);
        KT64(2, 0, k4);
        KT64(3, 1, k5);
        KT64(0, 2, k6);
    }

    // ---- epilogue: out = acc*(s_o*D_m/8) + bias ----
    // C/D layout: col = lane&15, row = (lane>>4)*4 + reg
    float sv[4], bv[4];
#pragma unroll
    for (int ni = 0; ni < 4; ++ni) {
        const int col = bn * 256 + wc * 64 + ni * 16 + l15;
        sv[ni] = sArr[col] * 0.125f;
        bv[ni] = bias[col];
    }

    const int crow0 = bm * 256 + wr * 128;
    const int ccol = bn * 256 + wc * 64 + l15;
#pragma unroll
    for (int mi = 0; mi < 8; ++mi) {
#pragma unroll
        for (int rr = 0; rr < 4; ++rr) {
            const int row = crow0 + mi * 16 + (lane >> 4) * 4 + rr;
            const float rd = rdel[row];
            float* Crow = C + (size_t)row * N;
#pragma unroll
            for (int ni = 0; ni < 4; ++ni)
                Crow[ccol + ni * 16] =
                    (float)acc[mi][ni][rr] * (sv[ni] * rd) + bv[ni];
        }
    }
}

// ---------------------------------------------------------------------------
extern "C" void kernel_launch(void* const* d_in, const int* in_sizes, int n_in,
                              void* d_out, int out_size, void* d_ws, size_t ws_size,
                              hipStream_t stream) {
    const float* x      = (const float*)d_in[0];
    const float* weight = (const float*)d_in[1];
    const float* bias   = (const float*)d_in[2];
    const float* ow     = (const float*)d_in[3];
    const int*   idx    = (const int*)d_in[4];

    const int OC    = in_sizes[2];
    const int n_out = in_sizes[4];
    const int IC    = in_sizes[1] / OC;      // 4096
    const int M     = in_sizes[0] / IC;      // 8192
    const int K2    = IC + 256;              // 4352
    float* out = (float*)d_out;

    char* ws = (char*)d_ws;
    signed char* qx = (signed char*)ws;                                 // M*K2
    signed char* qw = (signed char*)(ws + (size_t)M * K2);              // OC*K2
    float* sArr = (float*)(ws + (size_t)M * K2 + (size_t)OC * K2);      // OC
    float* rdel = sArr + OC;                                            // M

    quant_sign_kernel<<<OC, 256, 0, stream>>>(weight, ow, idx, qw, sArr,
                                              IC, K2, n_out);
    quant_x_kernel<<<M, 256, 0, stream>>>((const float4*)x, idx, qx, rdel,
                                          IC, K2, n_out);

    hipFuncSetAttribute((const void*)gemm_i8_kernel,
                        hipFuncAttributeMaxDynamicSharedMemorySize, 131072);
    const int NBM = M / 256, NBN = OC / 256;
    gemm_i8_kernel<<<dim3(NBM * NBN), dim3(512), 131072, stream>>>(
        qx, qw, bias, sArr, rdel, out, M, OC, K2, NBN);
}